// Round 3
// baseline (78.187 us; speedup 1.0000x reference)
//
#include <hip/hip_runtime.h>
#include <hip/hip_bf16.h>

typedef __attribute__((ext_vector_type(4))) float f32x4;
typedef __attribute__((ext_vector_type(8))) short s16x8;

#define M_DIM 256
#define N_DIM 16384
#define K_DIM 2048
#define BM 64
#define BN 256
#define BK 32
#define NKT 64            // K tiles of 32
#define TPG 8             // tiles per staging group
#define NG 8              // groups
#define TEMP_INV 20.0f
#define SPECIAL 5554
#define IGNORE_IDX 1023

__device__ __forceinline__ short f2bf(float x) {
  __hip_bfloat16 h = __float2bfloat16(x);
  return __builtin_bit_cast(short, h);
}

__device__ __forceinline__ void gload_lds16(const void* g, void* l) {
  __builtin_amdgcn_global_load_lds((const __attribute__((address_space(1))) void*)g,
                                   (__attribute__((address_space(3))) void*)l, 16, 0, 0);
}

// Kernel 0: inputs f32 [256][2048] -> bf16, tiled+swizzled for linear global_load_lds.
// Global chunk index fid = bm*16384 + kt*256 + q, q = r*4 + c'. Chunk holds
// A[bm*64 + r][kt*32 + c*8 .. +8] with c = c' ^ ((r>>1)&3)  (LDS bank swizzle).
__global__ __launch_bounds__(256) void convA(const float* __restrict__ A,
                                             short* __restrict__ Abf) {
  int fid = blockIdx.x * 256 + threadIdx.x;  // 0..65535
  int bm = fid >> 14;
  int kt = (fid >> 8) & 63;
  int q = fid & 255;
  int r = q >> 2;
  int cp = q & 3;
  int c = cp ^ ((r >> 1) & 3);
  const float* src = A + (size_t)(bm * BM + r) * K_DIM + kt * BK + c * 8;
  float4 lo = *(const float4*)src;
  float4 hi = *(const float4*)(src + 4);
  s16x8 h;
  h[0] = f2bf(lo.x); h[1] = f2bf(lo.y); h[2] = f2bf(lo.z); h[3] = f2bf(lo.w);
  h[4] = f2bf(hi.x); h[5] = f2bf(hi.y); h[6] = f2bf(hi.z); h[7] = f2bf(hi.w);
  *reinterpret_cast<s16x8*>(Abf + (size_t)fid * 8) = h;
}

// Fused GEMM + exp-rowsum + target capture.
// B (features, f32, 128 MB) goes HBM -> registers -> bf16 frags, wave-private,
// never through LDS, pipelined 2 K-tiles deep. A staged via global_load_lds in
// 8-tile groups (8 barriers total); B regs live across barriers.
__global__ __launch_bounds__(512, 1) void gemm_fused(
    const short* __restrict__ Abf, const float* __restrict__ B,
    const int* __restrict__ targets,
    float* __restrict__ partial,    // [64 bn][256 rows]
    float* __restrict__ targ) {     // [256]
  __shared__ __align__(16) short Abuf[2][TPG * BM * BK];  // 2 x 32 KB
  __shared__ int tcs[BM];
  __shared__ float rsum[BM][8];

  // XCD swizzle: 4 bm-blocks of one bn panel land on the same XCD (L2 reuse x4).
  int bid = blockIdx.x;
  int lbid = (bid & 7) * 32 + (bid >> 3);
  int bm = lbid & 3;    // 0..3
  int bn = lbid >> 2;   // 0..63

  int tid = threadIdx.x;
  int wave = tid >> 6;  // 0..7 -> owns 32 N-cols
  int lane = tid & 63;
  int rl = lane & 15;
  int kq = lane >> 4;   // k-slot 0..3

  if (tid < BM) {
    int tt = targets[bm * BM + tid] - 1;
    if (tt == SPECIAL) tt = IGNORE_IDX;
    tcs[tid] = tt < 0 ? 0 : (tt > N_DIM - 1 ? N_DIM - 1 : tt);
  }

  // B operand addr: col = bn*256 + wave*32 + ni*16 + rl ; k = kt*32 + kq*8
  const float* bptr0 = B + (size_t)(bn * BN + wave * 32 + rl) * K_DIM + kq * 8;

  int bmBase = bm * (NKT * 256);  // global chunk base for this bm

  // A frag ds_read offset (shorts): tile t*2048 + frag m*512 + rl*32 + swz-slot*8
  int soff = rl * 32 + ((kq ^ ((rl >> 1) & 3)) << 3);

  f32x4 acc[4][2];
#pragma unroll
  for (int m = 0; m < 4; ++m)
#pragma unroll
    for (int ni = 0; ni < 2; ++ni) acc[m][ni] = f32x4{0.f, 0.f, 0.f, 0.f};

  float4 Bpre[2][2][2];  // [tile parity][ni][half]; all static indices

#define LOADB(par, kt)                                                        \
  {                                                                           \
    const float* _p = bptr0 + (size_t)(kt) * BK;                              \
    Bpre[par][0][0] = *(const float4*)_p;                                     \
    Bpre[par][0][1] = *(const float4*)(_p + 4);                               \
    Bpre[par][1][0] = *(const float4*)(_p + 16 * K_DIM);                      \
    Bpre[par][1][1] = *(const float4*)(_p + 16 * K_DIM + 4);                  \
  }

#define STAGE(g, bufidx)                                                      \
  {                                                                           \
    int _base = bmBase + (g) * (TPG * 256);                                   \
    char* _lb = (char*)&Abuf[bufidx][0];                                      \
    _Pragma("unroll") for (int _j = 0; _j < 4; ++_j) {                        \
      int _ci = _j * 512 + tid;                                               \
      gload_lds16(Abf + ((size_t)(_base + _ci) << 3), _lb + _ci * 16);        \
    }                                                                         \
  }

  STAGE(0, 0);
  LOADB(0, 0);
  LOADB(1, 1);
  __syncthreads();

  for (int g = 0; g < NG; ++g) {
    if (g + 1 < NG) STAGE(g + 1, (g + 1) & 1);
    const short* ab = &Abuf[g & 1][0];
#pragma unroll
    for (int t = 0; t < TPG; ++t) {
      // convert current B tile (loaded 2 tiles ago) to bf16 frags
      s16x8 bf[2];
#pragma unroll
      for (int ni = 0; ni < 2; ++ni) {
        float4 lo = Bpre[t & 1][ni][0], hi = Bpre[t & 1][ni][1];
        s16x8 h;
        h[0] = f2bf(lo.x); h[1] = f2bf(lo.y); h[2] = f2bf(lo.z); h[3] = f2bf(lo.w);
        h[4] = f2bf(hi.x); h[5] = f2bf(hi.y); h[6] = f2bf(hi.z); h[7] = f2bf(hi.w);
        bf[ni] = h;
      }
      int ktB = g * TPG + t + 2;   // prefetch 2 tiles ahead (crosses group boundary)
      if (ktB < NKT) LOADB(t & 1, ktB);

      s16x8 af[4];
#pragma unroll
      for (int m = 0; m < 4; ++m)
        af[m] = *reinterpret_cast<const s16x8*>(ab + t * 2048 + m * 512 + soff);

#pragma unroll
      for (int m = 0; m < 4; ++m)
#pragma unroll
        for (int ni = 0; ni < 2; ++ni)
          acc[m][ni] = __builtin_amdgcn_mfma_f32_16x16x32_bf16(
              af[m], bf[ni], acc[m][ni], 0, 0, 0);
    }
    __syncthreads();  // A(g+1) staged; B regs survive the vmcnt drain
  }

  // Epilogue: D row = kq*4 + r (+m*16), col = wave*32 + ni*16 + rl
  int colbase = bn * BN + wave * 32 + rl;
#pragma unroll
  for (int m = 0; m < 4; ++m) {
#pragma unroll
    for (int r = 0; r < 4; ++r) {
      int rloc = m * 16 + kq * 4 + r;
      int tc = tcs[rloc];
      float s = 0.f;
#pragma unroll
      for (int ni = 0; ni < 2; ++ni) {
        float logit = acc[m][ni][r] * TEMP_INV;
        if (colbase + ni * 16 == tc) targ[bm * BM + rloc] = logit;
        s += __expf(logit);
      }
#pragma unroll
      for (int msk = 1; msk < 16; msk <<= 1) s += __shfl_xor(s, msk, 64);
      if (rl == 0) rsum[rloc][wave] = s;
    }
  }
  __syncthreads();
  if (tid < BM) {
    float s = 0.f;
#pragma unroll
    for (int w = 0; w < 8; ++w) s += rsum[tid][w];
    partial[(size_t)bn * M_DIM + bm * BM + tid] = s;
  }
#undef LOADB
#undef STAGE
}

__global__ __launch_bounds__(256) void finalize(
    const float* __restrict__ partial, const float* __restrict__ targ,
    const int* __restrict__ targets, float* __restrict__ out) {
  int r = threadIdx.x;  // 256 rows
  float s = 0.f;
  for (int j = 0; j < 64; ++j) s += partial[(size_t)j * M_DIM + r];
  int t = targets[r] - 1;
  if (t == SPECIAL) t = IGNORE_IDX;
  bool valid = (t >= 0) && (t != IGNORE_IDX);
  float nl = logf(s) - targ[r];
  float sv = valid ? nl : 0.0f;
  float cv = valid ? 1.0f : 0.0f;
#pragma unroll
  for (int m = 1; m < 64; m <<= 1) {
    sv += __shfl_xor(sv, m, 64);
    cv += __shfl_xor(cv, m, 64);
  }
  __shared__ float ss[4], cc[4];
  int wid = r >> 6, lane = r & 63;
  if (lane == 0) { ss[wid] = sv; cc[wid] = cv; }
  __syncthreads();
  if (r == 0) {
    float S = ss[0] + ss[1] + ss[2] + ss[3];
    float C = cc[0] + cc[1] + cc[2] + cc[3];
    out[0] = S / fmaxf(C, 1.0f);
  }
}

extern "C" void kernel_launch(void* const* d_in, const int* in_sizes, int n_in,
                              void* d_out, int out_size, void* d_ws, size_t ws_size,
                              hipStream_t stream) {
  const float* inputs   = (const float*)d_in[0];  // [256, 2048]
  const int*   targets  = (const int*)d_in[1];    // [256]
  const float* features = (const float*)d_in[2];  // [16384, 2048]
  float* out = (float*)d_out;

  short* Abf     = (short*)d_ws;                        // 65536 chunks * 16B = 1 MB
  float* partial = (float*)((char*)d_ws + (1 << 20));   // [64][256] f32 = 64 KB
  float* targ    = partial + 64 * M_DIM;                // [256] f32

  convA<<<dim3(256), dim3(256), 0, stream>>>(inputs, Abf);
  gemm_fused<<<dim3(256), dim3(512), 0, stream>>>(Abf, features, targets, partial, targ);
  finalize<<<dim3(1), dim3(256), 0, stream>>>(partial, targ, targets, out);
}

// Round 4
// 49.714 us; speedup vs baseline: 1.5728x; 1.5728x over previous
//
#include <hip/hip_runtime.h>
#include <hip/hip_bf16.h>

typedef __attribute__((ext_vector_type(4))) float f32x4;
typedef __attribute__((ext_vector_type(8))) short s16x8;
typedef __attribute__((ext_vector_type(4))) short s16x4;

#define M_DIM 256
#define N_DIM 16384
#define K_DIM 2048
#define BM 64
#define BN 128
#define BK 64
#define NKT 32            // K tiles of 64
#define TEMP_INV 20.0f
#define SPECIAL 5554
#define IGNORE_IDX 1023

__device__ __forceinline__ short f2bf(float x) {
  __hip_bfloat16 h = __float2bfloat16(x);
  return __builtin_bit_cast(short, h);
}

// Kernel 0: inputs f32 [256][2048] -> bf16 "LDS image": tile T = bm*32 + kt
// holds 512 chunks of 16B; chunk p = row*8 + s' where s' = s ^ (row&7),
// covering A[bm*64+row][kt*64 + s*8 .. +8]. GEMM stages it linearly and
// reads with the matching XOR (rule 21: swizzle both sides).
__global__ __launch_bounds__(256) void convA(const float* __restrict__ A,
                                             short* __restrict__ Abf) {
  int fid = blockIdx.x * 256 + threadIdx.x;  // 0..65535 chunks
  int T = fid >> 9;
  int p = fid & 511;
  int row = p >> 3;
  int s = (p & 7) ^ (row & 7);
  int bm = T >> 5;
  int kt = T & 31;
  const float* src = A + (size_t)(bm * BM + row) * K_DIM + kt * BK + s * 8;
  float4 lo = *(const float4*)src;
  float4 hi = *(const float4*)(src + 4);
  s16x8 h;
  h[0] = f2bf(lo.x); h[1] = f2bf(lo.y); h[2] = f2bf(lo.z); h[3] = f2bf(lo.w);
  h[4] = f2bf(hi.x); h[5] = f2bf(hi.y); h[6] = f2bf(hi.z); h[7] = f2bf(hi.w);
  *reinterpret_cast<s16x8*>(Abf + (size_t)fid * 8) = h;
}

struct Stage {
  float4 b[8];   // B f32: thread's 8 chunks (row j*16+(tid>>4), 16B at col (tid&15)*4)
  s16x8 a[2];    // A bf16 chunks tid and 256+tid
};

// Fused GEMM + exp-rowsum + target capture. 2-phase pipeline, depth-2 reg
// prefetch, raw barrier (no vmcnt drain), bf16 LDS with XOR-slot swizzle.
__global__ __launch_bounds__(256, 2) void gemm_fused(
    const short* __restrict__ Abf, const float* __restrict__ B,
    const int* __restrict__ targets,
    float* __restrict__ partial,    // [128 bn][256 rows]
    float* __restrict__ targ) {     // [256]
  __shared__ __align__(16) short Al[2][BM * 64];   // 64 rows x 128B, 2 x 8 KB
  __shared__ __align__(16) short Bl[2][BN * 64];   // 128 rows x 128B, 2 x 16 KB
  __shared__ int tcs[BM];
  __shared__ float rsum[BM][2];

  int bid = blockIdx.x;
  int lbid = (bid & 7) * 64 + (bid >> 3);  // bijective (512 % 8 == 0)
  int bm = lbid & 3;    // 0..3
  int bn = lbid >> 2;   // 0..127; 16 consecutive panels x 4 bm per XCD

  int tid = threadIdx.x;
  int wave = tid >> 6;
  int lane = tid & 63;
  int rl = lane & 15;
  int kq = lane >> 4;
  int wm = wave >> 1;   // 0..1 -> 32 rows
  int wn = wave & 1;    // 0..1 -> 64 cols

  if (tid < BM) {
    int tt = targets[bm * BM + tid] - 1;
    if (tt == SPECIAL) tt = IGNORE_IDX;
    tcs[tid] = tt < 0 ? 0 : (tt > N_DIM - 1 ? N_DIM - 1 : tt);
  }

  // B source: thread covers chunk (row = j*16 + (tid>>4), 16B at (tid&15)*4 floats)
  const float* bbase = B + (size_t)(bn * BN + (tid >> 4)) * K_DIM + (tid & 15) * 4;
  const s16x8* abase = (const s16x8*)Abf + (size_t)(bm * NKT) * 512 + tid;

  f32x4 acc[2][4];
#pragma unroll
  for (int m = 0; m < 2; ++m)
#pragma unroll
    for (int n = 0; n < 4; ++n) acc[m][n] = f32x4{0.f, 0.f, 0.f, 0.f};

  Stage S0, S1;

#define LOAD_STAGE(kt, S)                                                     \
  {                                                                           \
    const float* _bp = bbase + (size_t)(kt) * BK;                             \
    _Pragma("unroll") for (int _j = 0; _j < 8; ++_j)                          \
        (S).b[_j] = *(const float4*)(_bp + (size_t)_j * 16 * K_DIM);          \
    const s16x8* _ap = abase + (size_t)(kt) * 512;                            \
    (S).a[0] = _ap[0];                                                        \
    (S).a[1] = _ap[256];                                                      \
  }

#define CVT_WRITE(S, buf)                                                     \
  {                                                                           \
    short* _bl = &Bl[buf][0];                                                 \
    int _cc = tid & 15;                                                       \
    _Pragma("unroll") for (int _j = 0; _j < 8; ++_j) {                        \
      int _row = _j * 16 + (tid >> 4);                                        \
      int _off = _row * 64 + (((_cc >> 1) ^ (_row & 7)) * 8) + (_cc & 1) * 4; \
      s16x4 _h;                                                               \
      _h[0] = f2bf((S).b[_j].x); _h[1] = f2bf((S).b[_j].y);                   \
      _h[2] = f2bf((S).b[_j].z); _h[3] = f2bf((S).b[_j].w);                   \
      *reinterpret_cast<s16x4*>(_bl + _off) = _h;                             \
    }                                                                         \
    short* _al = &Al[buf][0];                                                 \
    *reinterpret_cast<s16x8*>(_al + (size_t)tid * 8) = (S).a[0];              \
    *reinterpret_cast<s16x8*>(_al + (size_t)(256 + tid) * 8) = (S).a[1];      \
  }

#define BARRIER() asm volatile("s_waitcnt lgkmcnt(0)\n\ts_barrier" ::: "memory")

#define BODY(t, SL, SW)                                                       \
  {                                                                           \
    if ((t) + 2 < NKT) LOAD_STAGE((t) + 2, SL);                               \
    const int _par = (t) & 1;                                                 \
    const short* _alr = &Al[_par][0];                                         \
    const short* _blr = &Bl[_par][0];                                         \
    s16x8 _af[2][2], _bf[4][2];                                               \
    _Pragma("unroll") for (int _m = 0; _m < 2; ++_m) {                        \
      int _row = wm * 32 + _m * 16 + rl;                                      \
      _Pragma("unroll") for (int _kk = 0; _kk < 2; ++_kk) {                   \
        int _s = _kk * 4 + kq;                                                \
        _af[_m][_kk] = *reinterpret_cast<const s16x8*>(                       \
            _alr + _row * 64 + ((_s ^ (_row & 7)) * 8));                      \
      }                                                                       \
    }                                                                         \
    _Pragma("unroll") for (int _n = 0; _n < 4; ++_n) {                        \
      int _row = wn * 64 + _n * 16 + rl;                                      \
      _Pragma("unroll") for (int _kk = 0; _kk < 2; ++_kk) {                   \
        int _s = _kk * 4 + kq;                                                \
        _bf[_n][_kk] = *reinterpret_cast<const s16x8*>(                       \
            _blr + _row * 64 + ((_s ^ (_row & 7)) * 8));                      \
      }                                                                       \
    }                                                                         \
    _Pragma("unroll") for (int _kk = 0; _kk < 2; ++_kk)                       \
        _Pragma("unroll") for (int _m = 0; _m < 2; ++_m)                      \
            _Pragma("unroll") for (int _n = 0; _n < 4; ++_n)                  \
                acc[_m][_n] = __builtin_amdgcn_mfma_f32_16x16x32_bf16(        \
                    _af[_m][_kk], _bf[_n][_kk], acc[_m][_n], 0, 0, 0);        \
    if ((t) + 1 < NKT) {                                                      \
      CVT_WRITE(SW, ((t) + 1) & 1);                                           \
      BARRIER();                                                              \
    }                                                                         \
  }

  // prologue: loads(0)->S0, loads(1)->S1, write tile0, barrier (loads(1) stay in flight)
  LOAD_STAGE(0, S0);
  LOAD_STAGE(1, S1);
  CVT_WRITE(S0, 0);
  BARRIER();

  for (int tb = 0; tb < NKT; tb += 2) {
    BODY(tb, S0, S1);
    BODY(tb + 1, S1, S0);
  }

  // ---- fused epilogue ----
  int colbase = bn * BN + wn * 64 + rl;
#pragma unroll
  for (int m = 0; m < 2; ++m) {
#pragma unroll
    for (int r = 0; r < 4; ++r) {
      int rloc = wm * 32 + m * 16 + kq * 4 + r;
      int tc = tcs[rloc];
      float s = 0.f;
#pragma unroll
      for (int n = 0; n < 4; ++n) {
        float logit = acc[m][n][r] * TEMP_INV;
        if (colbase + n * 16 == tc) targ[bm * BM + rloc] = logit;
        s += __expf(logit);
      }
#pragma unroll
      for (int msk = 1; msk < 16; msk <<= 1) s += __shfl_xor(s, msk, 64);
      if (rl == 0) rsum[rloc][wn] = s;
    }
  }
  __syncthreads();
  if (tid < BM) {
    float s = rsum[tid][0] + rsum[tid][1];
    partial[(size_t)bn * M_DIM + bm * BM + tid] = s;
  }
#undef LOAD_STAGE
#undef CVT_WRITE
#undef BARRIER
#undef BODY
}

__global__ __launch_bounds__(256) void finalize(
    const float* __restrict__ partial, const float* __restrict__ targ,
    const int* __restrict__ targets, float* __restrict__ out) {
  int r = threadIdx.x;  // 256 rows
  float s = 0.f;
  for (int j = 0; j < 128; ++j) s += partial[(size_t)j * M_DIM + r];
  int t = targets[r] - 1;
  if (t == SPECIAL) t = IGNORE_IDX;
  bool valid = (t >= 0) && (t != IGNORE_IDX);
  float nl = logf(s) - targ[r];
  float sv = valid ? nl : 0.0f;
  float cv = valid ? 1.0f : 0.0f;
#pragma unroll
  for (int m = 1; m < 64; m <<= 1) {
    sv += __shfl_xor(sv, m, 64);
    cv += __shfl_xor(cv, m, 64);
  }
  __shared__ float ss[4], cc[4];
  int wid = r >> 6, lane = r & 63;
  if (lane == 0) { ss[wid] = sv; cc[wid] = cv; }
  __syncthreads();
  if (r == 0) {
    float S = ss[0] + ss[1] + ss[2] + ss[3];
    float C = cc[0] + cc[1] + cc[2] + cc[3];
    out[0] = S / fmaxf(C, 1.0f);
  }
}

extern "C" void kernel_launch(void* const* d_in, const int* in_sizes, int n_in,
                              void* d_out, int out_size, void* d_ws, size_t ws_size,
                              hipStream_t stream) {
  const float* inputs   = (const float*)d_in[0];  // [256, 2048]
  const int*   targets  = (const int*)d_in[1];    // [256]
  const float* features = (const float*)d_in[2];  // [16384, 2048]
  float* out = (float*)d_out;

  short* Abf     = (short*)d_ws;                        // 1 MB bf16 LDS-image
  float* partial = (float*)((char*)d_ws + (1 << 20));   // [128][256] f32 = 128 KB
  float* targ    = partial + 128 * M_DIM;               // [256] f32

  convA<<<dim3(256), dim3(256), 0, stream>>>(inputs, Abf);
  gemm_fused<<<dim3(512), dim3(256), 0, stream>>>(Abf, features, targets, partial, targ);
  finalize<<<dim3(1), dim3(256), 0, stream>>>(partial, targ, targets, out);
}